// Round 10
// baseline (175.010 us; speedup 1.0000x reference)
//
#include <hip/hip_runtime.h>
#include <hip/hip_bf16.h>

#define N 8192
#define D 128
#define WEIGHT 0.01f
#define NTILES 64            // N / 128
#define NBLK 2080            // NTILES*(NTILES+1)/2
#define PBLK 512             // persistent blocks = 2 per CU (co-resident, verified capacity)

typedef __bf16 bf16x8 __attribute__((ext_vector_type(8)));
typedef float floatx4 __attribute__((ext_vector_type(4)));

// ---- Kernel 1: L2-normalize rows (fp32) -> bf16, stored XOR-SWIZZLED
//      (16B chunk c of row r at position c ^ (r & 15)); zero sync cells.
__global__ __launch_bounds__(256) void k_norm(const float* __restrict__ x,
                                              __hip_bfloat16* __restrict__ fb,
                                              float* __restrict__ acc,
                                              unsigned* __restrict__ done,
                                              unsigned* __restrict__ cnt2) {
    int gid = blockIdx.x * 256 + threadIdx.x;   // 512 blocks
    if (gid == 0) { *acc = 0.0f; *done = 0u; *cnt2 = 0u; }
    int row = gid >> 4;                          // 16 threads per row
    int c   = gid & 15;
    const float4* xr = (const float4*)(x + (size_t)row * D + c * 8);
    float4 f0 = xr[0], f1 = xr[1];
    float s = f0.x * f0.x + f0.y * f0.y + f0.z * f0.z + f0.w * f0.w
            + f1.x * f1.x + f1.y * f1.y + f1.z * f1.z + f1.w * f1.w;
    s += __shfl_xor(s, 1, 64);
    s += __shfl_xor(s, 2, 64);
    s += __shfl_xor(s, 4, 64);
    s += __shfl_xor(s, 8, 64);
    float inv = 1.0f / fmaxf(sqrtf(s), 1e-12f);
    union { __hip_bfloat16 h[8]; uint4 u; } pk;
    pk.h[0] = __float2bfloat16(f0.x * inv);
    pk.h[1] = __float2bfloat16(f0.y * inv);
    pk.h[2] = __float2bfloat16(f0.z * inv);
    pk.h[3] = __float2bfloat16(f0.w * inv);
    pk.h[4] = __float2bfloat16(f1.x * inv);
    pk.h[5] = __float2bfloat16(f1.y * inv);
    pk.h[6] = __float2bfloat16(f1.z * inv);
    pk.h[7] = __float2bfloat16(f1.w * inv);
    ((uint4*)fb)[(size_t)row * 16 + (c ^ (row & 15))] = pk.u;
}

// ---- Kernel 2 (persistent, fused): gram partials -> grid barrier -> reduce+final.
//      512 blocks x 256 threads = 2 blocks/CU co-resident (66.5 KB LDS, 104 VGPR):
//      one block's compute overlaps its CU-mate's staging drain (the R6 overlap
//      that R9's 1-block/CU config lost). ~4 tiles per block, 2 barriers/tile.
__global__ __launch_bounds__(256, 2) void k_main(const __hip_bfloat16* __restrict__ fb,
                                                 float* __restrict__ Prow,
                                                 float* __restrict__ Pcol,
                                                 float* __restrict__ p,
                                                 float* __restrict__ ep,
                                                 float* __restrict__ acc,
                                                 unsigned* __restrict__ done,
                                                 unsigned* __restrict__ cnt2,
                                                 float* __restrict__ out) {
    __shared__ uint4 Ab[2048];           // pre-swizzled tile rows (32 KB)
    __shared__ uint4 Bb[2048];
    __shared__ float PR[2][128];
    __shared__ float PC[2][128];
    __shared__ float swred[4];

    const int t = threadIdx.x;
    const int lane = t & 63;
    const int wid  = t >> 6;             // 4 waves, 2x2
    const int wrow = wid >> 1, wcol = wid & 1;
    const int col0 = lane & 15;
    const int quad = lane >> 4;
    const uint4* gf = (const uint4*)fb;

    // ======== Phase 1: gram partials over strided tiles ========
    for (int tile = blockIdx.x; tile < NBLK; tile += PBLK) {
        int bi = 0;
        while ((bi + 1) * NTILES - (bi + 1) * bi / 2 <= tile) ++bi;
        int bj = bi + (tile - (bi * NTILES - bi * (bi - 1) / 2));
        const int rbase = bi * 128, cbase = bj * 128;

        const uint4* gA = gf + (size_t)rbase * 16;
        const uint4* gB = gf + (size_t)cbase * 16;
        #pragma unroll
        for (int i = 0; i < 8; ++i) {
            int ca = wid * 512 + i * 64;
            __builtin_amdgcn_global_load_lds(
                (const __attribute__((address_space(1))) void*)(gA + ca + lane),
                (__attribute__((address_space(3))) void*)&Ab[ca], 16, 0, 0);
            __builtin_amdgcn_global_load_lds(
                (const __attribute__((address_space(1))) void*)(gB + ca + lane),
                (__attribute__((address_space(3))) void*)&Bb[ca], 16, 0, 0);
        }
        __syncthreads();                 // drain DMA (CU-mate block computes meanwhile)

        floatx4 acc4[4][4];
        #pragma unroll
        for (int a = 0; a < 4; ++a)
            #pragma unroll
            for (int c = 0; c < 4; ++c)
                acc4[a][c] = (floatx4){0.0f, 0.0f, 0.0f, 0.0f};

        #pragma unroll
        for (int ks = 0; ks < 4; ++ks) {
            bf16x8 af[4], bfr[4];
            int j = ks * 4 + quad;
            int jsw = j ^ col0;
            #pragma unroll
            for (int mt = 0; mt < 4; ++mt) {
                int rl = wrow * 64 + mt * 16 + col0;
                af[mt] = *(const bf16x8*)&Ab[rl * 16 + jsw];
            }
            #pragma unroll
            for (int nt = 0; nt < 4; ++nt) {
                int cl = wcol * 64 + nt * 16 + col0;
                bfr[nt] = *(const bf16x8*)&Bb[cl * 16 + jsw];
            }
            #pragma unroll
            for (int mt = 0; mt < 4; ++mt)
                #pragma unroll
                for (int nt = 0; nt < 4; ++nt)
                    acc4[mt][nt] = __builtin_amdgcn_mfma_f32_16x16x32_bf16(af[mt], bfr[nt], acc4[mt][nt], 0, 0, 0);
        }

        float v[16];
        float colpart[4];
        #pragma unroll
        for (int m = 0; m < 16; ++m) v[m] = 0.0f;
        #pragma unroll
        for (int m = 0; m < 4; ++m) colpart[m] = 0.0f;

        if (bj > bi + 1) {
            #pragma unroll
            for (int mt = 0; mt < 4; ++mt)
                #pragma unroll
                for (int nt = 0; nt < 4; ++nt)
                    #pragma unroll
                    for (int reg = 0; reg < 4; ++reg) {
                        float e = __expf(acc4[mt][nt][reg]);
                        v[mt * 4 + reg] += e;
                        colpart[nt] += e;
                    }
        } else {
            #pragma unroll
            for (int mt = 0; mt < 4; ++mt)
                #pragma unroll
                for (int nt = 0; nt < 4; ++nt)
                    #pragma unroll
                    for (int reg = 0; reg < 4; ++reg) {
                        int r = rbase + wrow * 64 + mt * 16 + quad * 4 + reg;
                        int c = cbase + wcol * 64 + nt * 16 + col0;
                        float s0 = acc4[mt][nt][reg];
                        float e = __expf(s0);
                        if (c == r + 1) { p[r] = s0; ep[r] = e; }
                        e = (c > r) ? e : 0.0f;
                        v[mt * 4 + reg] += e;
                        colpart[nt] += e;
                    }
        }

        // Row butterfly (value-halving, 15 shuffles).
        float v8[8];
        #pragma unroll
        for (int k = 0; k < 8; ++k) {
            float a = v[2 * k], bb = v[2 * k + 1];
            float give = (lane & 1) ? a : bb;
            float keep = (lane & 1) ? bb : a;
            v8[k] = keep + __shfl_xor(give, 1, 64);
        }
        float v4[4];
        #pragma unroll
        for (int k = 0; k < 4; ++k) {
            float a = v8[2 * k], bb = v8[2 * k + 1];
            float give = (lane & 2) ? a : bb;
            float keep = (lane & 2) ? bb : a;
            v4[k] = keep + __shfl_xor(give, 2, 64);
        }
        float v2[2];
        #pragma unroll
        for (int k = 0; k < 2; ++k) {
            float a = v4[2 * k], bb = v4[2 * k + 1];
            float give = (lane & 4) ? a : bb;
            float keep = (lane & 4) ? bb : a;
            v2[k] = keep + __shfl_xor(give, 4, 64);
        }
        {
            float a = v2[0], bb = v2[1];
            float give = (lane & 8) ? a : bb;
            float keep = (lane & 8) ? bb : a;
            float v1 = keep + __shfl_xor(give, 8, 64);
            int rowl = wrow * 64 + (col0 >> 2) * 16 + quad * 4 + (col0 & 3);
            PR[wcol][rowl] = v1;
        }
        {
            float c2[2];
            #pragma unroll
            for (int k = 0; k < 2; ++k) {
                float a = colpart[2 * k];
                float bb = colpart[2 * k + 1];
                float give = (lane & 16) ? a : bb;
                float keep = (lane & 16) ? bb : a;
                c2[k] = keep + __shfl_xor(give, 16, 64);
            }
            float a = c2[0], bb = c2[1];
            float give = (lane & 32) ? a : bb;
            float keep = (lane & 32) ? bb : a;
            float cv = keep + __shfl_xor(give, 32, 64);
            PC[wrow][wcol * 64 + lane] = cv;
        }
        __syncthreads();

        // Partial store reads only PR/PC; next iteration's DMA targets Ab/Bb,
        // and PR/PC are rewritten only after the next drain barrier -> no 3rd sync.
        if (t < 128) {
            Prow[(size_t)tile * 128 + t] = PR[0][t] + PR[1][t];
        } else {
            int c = t - 128;
            Pcol[(size_t)tile * 128 + c] = PC[0][c] + PC[1][c];
        }
    }

    // ======== Grid barrier (512 blocks, all co-resident at 2/CU) ========
    __threadfence();
    __syncthreads();
    if (t == 0) {
        __hip_atomic_fetch_add(done, 1u, __ATOMIC_RELEASE, __HIP_MEMORY_SCOPE_AGENT);
        while (__hip_atomic_load(done, __ATOMIC_ACQUIRE, __HIP_MEMORY_SCOPE_AGENT) < PBLK)
            __builtin_amdgcn_s_sleep(8);
    }
    __syncthreads();

    // ======== Phase 2: reduce + final ========
    // Block handles 16 rows: r = blockIdx.x*16 + (t>>4); 16 threads per row.
    {
        int r = blockIdx.x * 16 + (t >> 4);
        int tsub = t & 15;
        float s = 0.0f;
        // U[r]: strict-upper row sums over tiles (band, bj), bj = band..63.
        int band = r >> 7;
        int baseU = band * NTILES - band * (band - 1) / 2;
        for (int bj = band + tsub; bj < NTILES; bj += 16)
            s += Prow[(size_t)(baseU + bj - band) * 128 + (r & 127)];
        // L[c], c = r+1 (valid for r < N-1): col sums over tiles (bi, bandc).
        if (r < N - 1) {
            int c = r + 1;
            int bandc = c >> 7;
            for (int bi = tsub; bi <= bandc; bi += 16)
                s += Pcol[(size_t)(bi * NTILES - bi * (bi - 1) / 2 + (bandc - bi)) * 128 + (c & 127)];
        }
        s += __shfl_xor(s, 1, 64);
        s += __shfl_xor(s, 2, 64);
        s += __shfl_xor(s, 4, 64);
        s += __shfl_xor(s, 8, 64);
        float term = 0.0f;
        if (tsub == 0 && r < N - 1)
            term = __logf(s - ep[r]) - p[r];
        term += __shfl_xor(term, 16, 64);
        term += __shfl_xor(term, 32, 64);
        if (lane == 0) swred[wid] = term;
        __syncthreads();
        if (t == 0) {
            float part = swred[0] + swred[1] + swred[2] + swred[3];
            __hip_atomic_fetch_add(acc, part, __ATOMIC_RELEASE, __HIP_MEMORY_SCOPE_AGENT);
            unsigned old = __hip_atomic_fetch_add(cnt2, 1u, __ATOMIC_ACQ_REL, __HIP_MEMORY_SCOPE_AGENT);
            if (old == PBLK - 1) {
                float tot = __hip_atomic_load(acc, __ATOMIC_ACQUIRE, __HIP_MEMORY_SCOPE_AGENT);
                out[0] = -WEIGHT * tot / (float)N;
            }
        }
    }
}

extern "C" void kernel_launch(void* const* d_in, const int* in_sizes, int n_in,
                              void* d_out, int out_size, void* d_ws, size_t ws_size,
                              hipStream_t stream) {
    const float* x = (const float*)d_in[0];
    float* out = (float*)d_out;
    char* ws = (char*)d_ws;
    __hip_bfloat16* fb = (__hip_bfloat16*)ws;                  // N*D*2 = 2 MB
    float* p    = (float*)(ws + (size_t)N * D * 2);            // N floats
    float* ep   = p + N;
    float* Prow = ep + N;                                      // NBLK*128 floats
    float* Pcol = Prow + (size_t)NBLK * 128;
    float* acc  = Pcol + (size_t)NBLK * 128;
    unsigned* done = (unsigned*)(acc + 1);
    unsigned* cnt2 = done + 1;

    hipLaunchKernelGGL(k_norm, dim3(512),  dim3(256), 0, stream, x, fb, acc, done, cnt2);
    hipLaunchKernelGGL(k_main, dim3(PBLK), dim3(256), 0, stream, fb, Prow, Pcol, p, ep,
                       acc, done, cnt2, out);
}

// Round 11
// 95.332 us; speedup vs baseline: 1.8358x; 1.8358x over previous
//
#include <hip/hip_runtime.h>
#include <hip/hip_bf16.h>

#define N 8192
#define D 128
#define WEIGHT 0.01f
#define NTILES 64            // N / 128
#define NBLK 2080            // NTILES*(NTILES+1)/2

typedef __bf16 bf16x8 __attribute__((ext_vector_type(8)));
typedef float floatx4 __attribute__((ext_vector_type(4)));

// ---- Kernel 1: L2-normalize rows (fp32) -> bf16, stored XOR-SWIZZLED
//      (16B chunk c of row r at position c ^ (r & 15)); zero out[0] for k_tail's
//      atomic accumulation (harness re-poisons d_out to 0xAA before every run).
__global__ __launch_bounds__(256) void k_norm(const float* __restrict__ x,
                                              __hip_bfloat16* __restrict__ fb,
                                              float* __restrict__ out) {
    int gid = blockIdx.x * 256 + threadIdx.x;   // 512 blocks
    if (gid == 0) out[0] = 0.0f;
    int row = gid >> 4;                          // 16 threads per row
    int c   = gid & 15;
    const float4* xr = (const float4*)(x + (size_t)row * D + c * 8);
    float4 f0 = xr[0], f1 = xr[1];
    float s = f0.x * f0.x + f0.y * f0.y + f0.z * f0.z + f0.w * f0.w
            + f1.x * f1.x + f1.y * f1.y + f1.z * f1.z + f1.w * f1.w;
    s += __shfl_xor(s, 1, 64);
    s += __shfl_xor(s, 2, 64);
    s += __shfl_xor(s, 4, 64);
    s += __shfl_xor(s, 8, 64);                   // 16-lane group = one row
    float inv = 1.0f / fmaxf(sqrtf(s), 1e-12f);
    union { __hip_bfloat16 h[8]; uint4 u; } pk;
    pk.h[0] = __float2bfloat16(f0.x * inv);
    pk.h[1] = __float2bfloat16(f0.y * inv);
    pk.h[2] = __float2bfloat16(f0.z * inv);
    pk.h[3] = __float2bfloat16(f0.w * inv);
    pk.h[4] = __float2bfloat16(f1.x * inv);
    pk.h[5] = __float2bfloat16(f1.y * inv);
    pk.h[6] = __float2bfloat16(f1.z * inv);
    pk.h[7] = __float2bfloat16(f1.w * inv);
    ((uint4*)fb)[(size_t)row * 16 + (c ^ (row & 15))] = pk.u;
}

// ---- Kernel 2: upper-triangle 128x128 tiles of sim = F F^T (exact R6 body).
//      4 waves (2x2), wave tile 64x64; global_load_lds staging of pre-swizzled
//      rows; 66 KB LDS -> 2 blocks/CU (co-resident overlap is the win here).
__global__ __launch_bounds__(256, 2) void k_gram(const __hip_bfloat16* __restrict__ fb,
                                                 float* __restrict__ Prow,
                                                 float* __restrict__ Pcol,
                                                 float* __restrict__ p,
                                                 float* __restrict__ ep) {
    int b = blockIdx.x;                  // 0 .. 2079
    int bi = (int)((2.0 * NTILES + 1.0 - sqrt((2.0 * NTILES + 1.0) * (2.0 * NTILES + 1.0) - 8.0 * (double)b)) * 0.5);
    while (bi * NTILES - bi * (bi - 1) / 2 > b) --bi;
    while ((bi + 1) * NTILES - (bi + 1) * bi / 2 <= b) ++bi;
    int bj = bi + (b - (bi * NTILES - bi * (bi - 1) / 2));

    __shared__ uint4 Ab[2048];           // pre-swizzled tile rows (32 KB)
    __shared__ uint4 Bb[2048];
    __shared__ float PR[2][128];
    __shared__ float PC[2][128];

    const int t = threadIdx.x;
    const int lane = t & 63;
    const int wid  = t >> 6;             // 4 waves, 2x2
    const int wrow = wid >> 1, wcol = wid & 1;
    const int col0 = lane & 15;
    const int quad = lane >> 4;
    const int rbase = bi * 128, cbase = bj * 128;

    const uint4* gA = (const uint4*)fb + (size_t)rbase * 16;
    const uint4* gB = (const uint4*)fb + (size_t)cbase * 16;
    #pragma unroll
    for (int i = 0; i < 8; ++i) {
        int ca = wid * 512 + i * 64;
        __builtin_amdgcn_global_load_lds(
            (const __attribute__((address_space(1))) void*)(gA + ca + lane),
            (__attribute__((address_space(3))) void*)&Ab[ca], 16, 0, 0);
        __builtin_amdgcn_global_load_lds(
            (const __attribute__((address_space(1))) void*)(gB + ca + lane),
            (__attribute__((address_space(3))) void*)&Bb[ca], 16, 0, 0);
    }
    __syncthreads();

    floatx4 acc[4][4];
    #pragma unroll
    for (int a = 0; a < 4; ++a)
        #pragma unroll
        for (int c = 0; c < 4; ++c)
            acc[a][c] = (floatx4){0.0f, 0.0f, 0.0f, 0.0f};

    #pragma unroll
    for (int ks = 0; ks < 4; ++ks) {
        bf16x8 af[4], bfr[4];
        int j = ks * 4 + quad;
        int jsw = j ^ col0;
        #pragma unroll
        for (int mt = 0; mt < 4; ++mt) {
            int rl = wrow * 64 + mt * 16 + col0;
            af[mt] = *(const bf16x8*)&Ab[rl * 16 + jsw];
        }
        #pragma unroll
        for (int nt = 0; nt < 4; ++nt) {
            int cl = wcol * 64 + nt * 16 + col0;
            bfr[nt] = *(const bf16x8*)&Bb[cl * 16 + jsw];
        }
        #pragma unroll
        for (int mt = 0; mt < 4; ++mt)
            #pragma unroll
            for (int nt = 0; nt < 4; ++nt)
                acc[mt][nt] = __builtin_amdgcn_mfma_f32_16x16x32_bf16(af[mt], bfr[nt], acc[mt][nt], 0, 0, 0);
    }

    float v[16];
    float colpart[4];
    #pragma unroll
    for (int m = 0; m < 16; ++m) v[m] = 0.0f;
    #pragma unroll
    for (int m = 0; m < 4; ++m) colpart[m] = 0.0f;

    if (bj > bi + 1) {
        #pragma unroll
        for (int mt = 0; mt < 4; ++mt)
            #pragma unroll
            for (int nt = 0; nt < 4; ++nt)
                #pragma unroll
                for (int reg = 0; reg < 4; ++reg) {
                    float e = __expf(acc[mt][nt][reg]);
                    v[mt * 4 + reg] += e;
                    colpart[nt] += e;
                }
    } else {
        #pragma unroll
        for (int mt = 0; mt < 4; ++mt)
            #pragma unroll
            for (int nt = 0; nt < 4; ++nt)
                #pragma unroll
                for (int reg = 0; reg < 4; ++reg) {
                    int r = rbase + wrow * 64 + mt * 16 + quad * 4 + reg;
                    int c = cbase + wcol * 64 + nt * 16 + col0;
                    float s0 = acc[mt][nt][reg];
                    float e = __expf(s0);
                    if (c == r + 1) { p[r] = s0; ep[r] = e; }
                    e = (c > r) ? e : 0.0f;
                    v[mt * 4 + reg] += e;
                    colpart[nt] += e;
                }
    }

    // Row sums: value-halving butterfly (15 shuffles, all lanes distinct rows).
    float v8[8];
    #pragma unroll
    for (int k = 0; k < 8; ++k) {
        float a = v[2 * k], bb = v[2 * k + 1];
        float give = (lane & 1) ? a : bb;
        float keep = (lane & 1) ? bb : a;
        v8[k] = keep + __shfl_xor(give, 1, 64);
    }
    float v4[4];
    #pragma unroll
    for (int k = 0; k < 4; ++k) {
        float a = v8[2 * k], bb = v8[2 * k + 1];
        float give = (lane & 2) ? a : bb;
        float keep = (lane & 2) ? bb : a;
        v4[k] = keep + __shfl_xor(give, 2, 64);
    }
    float v2[2];
    #pragma unroll
    for (int k = 0; k < 2; ++k) {
        float a = v4[2 * k], bb = v4[2 * k + 1];
        float give = (lane & 4) ? a : bb;
        float keep = (lane & 4) ? bb : a;
        v2[k] = keep + __shfl_xor(give, 4, 64);
    }
    {
        float a = v2[0], bb = v2[1];
        float give = (lane & 8) ? a : bb;
        float keep = (lane & 8) ? bb : a;
        float v1 = keep + __shfl_xor(give, 8, 64);
        int rowl = wrow * 64 + (col0 >> 2) * 16 + quad * 4 + (col0 & 3);
        PR[wcol][rowl] = v1;
    }
    {
        float c2[2];
        #pragma unroll
        for (int k = 0; k < 2; ++k) {
            float a = colpart[2 * k];
            float bb = colpart[2 * k + 1];
            float give = (lane & 16) ? a : bb;
            float keep = (lane & 16) ? bb : a;
            c2[k] = keep + __shfl_xor(give, 16, 64);
        }
        float a = c2[0], bb = c2[1];
        float give = (lane & 32) ? a : bb;
        float keep = (lane & 32) ? bb : a;
        float cv = keep + __shfl_xor(give, 32, 64);
        PC[wrow][wcol * 64 + lane] = cv;
    }
    __syncthreads();

    if (t < 128) {
        Prow[(size_t)b * 128 + t] = PR[0][t] + PR[1][t];
    } else {
        int c = t - 128;
        Pcol[(size_t)b * 128 + c] = PC[0][c] + PC[1][c];
    }
}

// ---- Kernel 3 (merged reduce+final): per band of 128 rows, compute U[r]
//      (threads 0..127) and L[r+1] (threads 128..255) into LDS, then the log
//      terms, block-reduce, one scaled atomicAdd into out[0].
__global__ __launch_bounds__(256) void k_tail(const float* __restrict__ Prow,
                                              const float* __restrict__ Pcol,
                                              const float* __restrict__ p,
                                              const float* __restrict__ ep,
                                              float* __restrict__ out) {
    __shared__ float Ush[128];
    __shared__ float Lsh[128];           // Lsh[i] = L[band*128 + i + 1]
    __shared__ float sw[4];
    int band = blockIdx.x;               // 0..63
    int t = threadIdx.x;
    if (t < 128) {
        int baseU = band * NTILES - band * (band - 1) / 2;
        float s = 0.0f;
        for (int bj = band; bj < NTILES; ++bj)
            s += Prow[(size_t)(baseU + bj - band) * 128 + t];
        Ush[t] = s;
    } else {
        int c = band * 128 + (t - 128) + 1;      // base+1 .. base+128
        float s = 0.0f;
        if (c < N) {
            int bc = c >> 7;
            for (int bi = 0; bi <= bc; ++bi)
                s += Pcol[(size_t)(bi * NTILES - bi * (bi - 1) / 2 + (bc - bi)) * 128 + (c & 127)];
        }
        Lsh[t - 128] = s;
    }
    __syncthreads();
    float term = 0.0f;
    if (t < 128) {
        int r = band * 128 + t;
        if (r < N - 1)
            term = __logf(Ush[t] + Lsh[t] - ep[r]) - p[r];
    }
    #pragma unroll
    for (int m = 1; m < 64; m <<= 1) term += __shfl_xor(term, m, 64);
    int lane = t & 63, wd = t >> 6;
    if (lane == 0) sw[wd] = term;
    __syncthreads();
    if (t == 0) {
        float part = sw[0] + sw[1] + sw[2] + sw[3];
        atomicAdd(out, -WEIGHT * part / (float)N);
    }
}

extern "C" void kernel_launch(void* const* d_in, const int* in_sizes, int n_in,
                              void* d_out, int out_size, void* d_ws, size_t ws_size,
                              hipStream_t stream) {
    const float* x = (const float*)d_in[0];
    float* out = (float*)d_out;
    char* ws = (char*)d_ws;
    __hip_bfloat16* fb = (__hip_bfloat16*)ws;                  // N*D*2 = 2 MB
    float* p    = (float*)(ws + (size_t)N * D * 2);            // N floats
    float* ep   = p + N;
    float* Prow = ep + N;                                      // NBLK*128 floats
    float* Pcol = Prow + (size_t)NBLK * 128;

    hipLaunchKernelGGL(k_norm, dim3(512),  dim3(256), 0, stream, x, fb, out);
    hipLaunchKernelGGL(k_gram, dim3(NBLK), dim3(256), 0, stream, fb, Prow, Pcol, p, ep);
    hipLaunchKernelGGL(k_tail, dim3(64),   dim3(256), 0, stream, Prow, Pcol, p, ep, out);
}